// Round 1
// baseline (209.307 us; speedup 1.0000x reference)
//
#include <hip/hip_runtime.h>

// logsparseAttention == plain CAUSAL attention (no scale) at L=2048, SUB_LEN=5.
// Q,K,V [B,L,H,D] fp32; Out [B,H,L,D] fp32.  B=4, L=2048, H=16, D=64.
// R6: wave-level supertile pairing + exp2-domain softmax + defer-max.
//  - each wave owns 16 q of supertile pp AND 16 q of supertile 15-pp
//    (128-row supertiles): K/V fragment LDS reads are SHARED between the
//    two halves, no wave-slot is compute-idle, staged block-tiles halve
//    (25088 -> 12800) -> LDS pipe (the measured bottleneck) relieved.
//  - pp LUT {0,1,2,3,7,6,5,4}: co-resident block pairs (2/CU) have equal
//    total tile counts (50) under round-robin dispatch.
//  - K pre-scaled by log2(e) in conv_kv => softmax in exp2 domain: one
//    v_exp per element, no per-element mul.
//  - defer-max (THR=8 in log2 domain): skip alpha-rescale unless the tile
//    max exceeds m_run+8; P <= 2^8 = 256, safe in fp16.

typedef __attribute__((ext_vector_type(8))) short short8;
typedef __attribute__((ext_vector_type(4))) float floatx4;
typedef _Float16 half8 __attribute__((ext_vector_type(8)));
typedef _Float16 half4 __attribute__((ext_vector_type(4)));

#define NB 4
#define NL 2048
#define NH 16
#define ND 64
#define PADK 72   // 144B row stride, 16B-aligned
#define PADQ 72
#define LOG2E 1.44269504088896340736f

static __device__ __forceinline__ unsigned short f2bf(float f) {
    unsigned int u = __float_as_uint(f);
    u += 0x7fff + ((u >> 16) & 1);
    return (unsigned short)(u >> 16);
}
static __device__ __forceinline__ float bf2f(unsigned short h) {
    return __uint_as_float(((unsigned int)h) << 16);
}

// ---- fused prepass: K -> Kf [bh][key][d] fp16 * log2(e); V -> Vt [bh][d][key] fp16
__global__ __launch_bounds__(256)
void conv_kv(const float* __restrict__ Kg, const float* __restrict__ Vg,
             _Float16* __restrict__ Kf, _Float16* __restrict__ Vt) {
    __shared__ float tile[64][65];
    const int kt = blockIdx.x;       // key tile 0..31
    const int bh = blockIdx.y;       // 0..63
    const int b  = bh >> 4, h = bh & 15;
    const int t  = threadIdx.x;
    const int row = t >> 2;          // 0..63
    const int seg = (t & 3) * 16;    // 0..48
    const size_t gsrc = (((size_t)(b * NL + kt * 64 + row) * NH + h) << 6) + seg;
    {   // K: vectorized convert, folded log2(e) scale (exp2-domain softmax)
        float kv[16];
        #pragma unroll
        for (int i = 0; i < 16; i += 4) *(float4*)(kv + i) = *(const float4*)(Kg + gsrc + i);
        half8 o0, o1;
        #pragma unroll
        for (int j2 = 0; j2 < 8; ++j2) {
            o0[j2] = (_Float16)(kv[j2] * LOG2E);
            o1[j2] = (_Float16)(kv[8 + j2] * LOG2E);
        }
        _Float16* kd = Kf + (((size_t)(bh * NL + kt * 64 + row)) << 6) + seg;
        *(half8*)kd = o0;
        *(half8*)(kd + 8) = o1;
    }
    {   // V phase 1: fp32 tile into LDS
        #pragma unroll
        for (int i = 0; i < 16; i += 4) {
            float4 v = *(const float4*)(Vg + gsrc + i);
            tile[row][seg + i + 0] = v.x;
            tile[row][seg + i + 1] = v.y;
            tile[row][seg + i + 2] = v.z;
            tile[row][seg + i + 3] = v.w;
        }
    }
    __syncthreads();
    #pragma unroll
    for (int pass = 0; pass < 2; ++pass) {   // V phase 2: transpose out as fp16
        const int d  = pass * 32 + (t >> 3);
        const int kk = (t & 7) * 8;
        half8 o;
        #pragma unroll
        for (int j2 = 0; j2 < 8; ++j2) o[j2] = (_Float16)tile[kk + j2][d];
        *(half8*)(Vt + (((size_t)(bh * 64 + d)) << 11) + kt * 64 + kk) = o;
    }
}

// per-half online softmax (exp2 domain) + P pack + wave-private LDS transpose
static __device__ __forceinline__ void softmax_half(
    floatx4* s, bool domask, int j0, int qrow, int col, int quad,
    float& m_run, float& l_run, floatx4* of,
    _Float16* pbuf, half8& pf0, half8& pf1)
{
    if (domask) {
        #pragma unroll
        for (int f = 0; f < 4; ++f)
            #pragma unroll
            for (int r = 0; r < 4; ++r)
                if (j0 + f * 16 + quad * 4 + r > qrow) s[f][r] = -1e30f;
    }
    float mt = fmaxf(fmaxf(s[0][0], s[0][1]), fmaxf(s[0][2], s[0][3]));
    #pragma unroll
    for (int f = 1; f < 4; ++f)
        mt = fmaxf(mt, fmaxf(fmaxf(s[f][0], s[f][1]), fmaxf(s[f][2], s[f][3])));
    mt = fmaxf(mt, __shfl_xor(mt, 16));
    mt = fmaxf(mt, __shfl_xor(mt, 32));
    // defer-max: only rescale when the running max is beaten by >8 (log2 domain)
    if (__any(mt > m_run + 8.f)) {
        const float mn = fmaxf(m_run, mt);
        const float al = __builtin_amdgcn_exp2f(m_run - mn);
        #pragma unroll
        for (int mc = 0; mc < 4; ++mc) of[mc] *= al;
        l_run *= al;
        m_run = mn;
    }
    float ls = 0.f;
    #pragma unroll
    for (int f = 0; f < 4; ++f) {
        half4 hp;
        #pragma unroll
        for (int r = 0; r < 4; ++r) {
            const float p = __builtin_amdgcn_exp2f(s[f][r] - m_run);  // <= 2^8
            ls += p;
            hp[r] = (_Float16)p;
        }
        *(half4*)(pbuf + col * PADQ + f * 16 + quad * 4) = hp;
    }
    ls += __shfl_xor(ls, 16);
    ls += __shfl_xor(ls, 32);
    l_run += ls;
    pf0 = *(const half8*)(pbuf + col * PADQ + quad * 8);
    pf1 = *(const half8*)(pbuf + col * PADQ + 32 + quad * 8);
}

// ------------------------------- main kernel --------------------------------
__global__ __launch_bounds__(512, 4)
void lsattn_main(const float* __restrict__ Qg,
                 const _Float16* __restrict__ Kf,
                 const _Float16* __restrict__ Vt,
                 float* __restrict__ Og) {
    __shared__ alignas(16) _Float16 Ks[64 * PADK];       // [key][d]
    __shared__ alignas(16) _Float16 Vs[64 * PADK];       // [d][key]
    __shared__ alignas(16) _Float16 Ps[8 * 16 * PADQ];   // per-wave P [q][key]

    const int id   = (int)blockIdx.x;        // 0..511
    const int bh   = id & 63;
    const int j    = id >> 6;                // 0..7
    const int pp   = (j < 4) ? j : 11 - j;   // {0,1,2,3,7,6,5,4}: CU pairs balance
    const int tid  = threadIdx.x;
    const int lane = tid & 63;
    const int w    = tid >> 6;               // wave 0..7
    const int col  = lane & 15;
    const int quad = lane >> 4;
    const int wq   = w >> 2;                 // 0/1

    const int qrowA  = pp * 128 + w * 16 + col;          // supertile pp
    const int qrowB  = (15 - pp) * 128 + w * 16 + col;   // supertile 15-pp
    const int boundA = 2 * pp + wq;                      // last key-tile for A
    const int boundB = 30 - 2 * pp + wq;                 // last key-tile for B
    const int TB     = 31 - 2 * pp;                      // tiles staged: 0..TB

    // Q fragments (fp32->fp16), B-operand layout (K carries the log2e scale)
    half8 qfA[2], qfB[2];
    {
        const int b = bh >> 4, h = bh & 15;
        const float* qpA = Qg + (((size_t)(b * NL + qrowA) * NH + h) << 6) + quad * 8;
        const float* qpB = Qg + (((size_t)(b * NL + qrowB) * NH + h) << 6) + quad * 8;
        #pragma unroll
        for (int c = 0; c < 2; ++c) {
            float4 a0 = *(const float4*)(qpA + c * 32);
            float4 a1 = *(const float4*)(qpA + c * 32 + 4);
            qfA[c][0] = (_Float16)a0.x; qfA[c][1] = (_Float16)a0.y;
            qfA[c][2] = (_Float16)a0.z; qfA[c][3] = (_Float16)a0.w;
            qfA[c][4] = (_Float16)a1.x; qfA[c][5] = (_Float16)a1.y;
            qfA[c][6] = (_Float16)a1.z; qfA[c][7] = (_Float16)a1.w;
            float4 b0 = *(const float4*)(qpB + c * 32);
            float4 b1 = *(const float4*)(qpB + c * 32 + 4);
            qfB[c][0] = (_Float16)b0.x; qfB[c][1] = (_Float16)b0.y;
            qfB[c][2] = (_Float16)b0.z; qfB[c][3] = (_Float16)b0.w;
            qfB[c][4] = (_Float16)b1.x; qfB[c][5] = (_Float16)b1.y;
            qfB[c][6] = (_Float16)b1.z; qfB[c][7] = (_Float16)b1.w;
        }
    }

    floatx4 oA[4], oB[4];
    #pragma unroll
    for (int i = 0; i < 4; ++i) { oA[i] = floatx4{0.f,0.f,0.f,0.f}; oB[i] = floatx4{0.f,0.f,0.f,0.f}; }
    float mA = -1e30f, lA = 0.f, mB = -1e30f, lB = 0.f;

    // staging: thread covers 16B of one row; 512 threads cover 64 rows x 128B
    const int srow = tid >> 3;          // 0..63
    const int sseg = (tid & 7) * 8;     // 0..56
    const _Float16* kgb = Kf + (((size_t)(bh * NL)) << 6) + (srow << 6) + sseg;      // + t*4096
    const _Float16* vgb = Vt + (((size_t)bh) << 17) + ((size_t)srow << 11) + sseg;   // + t*64
    _Float16* pbuf = Ps + w * 16 * PADQ;

    // prefetch tile 0 into registers
    half8 kpre = *(const half8*)(kgb);
    half8 vpre = *(const half8*)(vgb);

    for (int t = 0; t <= TB; ++t) {
        const int j0 = t * 64;
        __syncthreads();                 // tile t-1 consumers done
        *(half8*)(Ks + srow * PADK + sseg) = kpre;
        *(half8*)(Vs + srow * PADK + sseg) = vpre;
        if (t < TB) {                    // issue next tile's loads BEFORE barrier
            kpre = *(const half8*)(kgb + (t + 1) * 4096);
            vpre = *(const half8*)(vgb + (t + 1) * 64);
        }
        __syncthreads();                 // tile t visible

        const bool actA = (t <= boundA);
        const bool actB = (t <= boundB);
        if (actA || actB) {
            // S^T = K * Q^T : K fragments SHARED between both halves
            floatx4 sA[4], sB[4];
            #pragma unroll
            for (int f = 0; f < 4; ++f) {
                const _Float16* kr = Ks + (f * 16 + col) * PADK + quad * 8;
                const half8 k0 = *(const half8*)(kr);
                const half8 k1 = *(const half8*)(kr + 32);
                if (actA) {
                    floatx4 a = floatx4{0.f,0.f,0.f,0.f};
                    a = __builtin_amdgcn_mfma_f32_16x16x32_f16(k0, qfA[0], a, 0, 0, 0);
                    a = __builtin_amdgcn_mfma_f32_16x16x32_f16(k1, qfA[1], a, 0, 0, 0);
                    sA[f] = a;
                }
                if (actB) {
                    floatx4 b = floatx4{0.f,0.f,0.f,0.f};
                    b = __builtin_amdgcn_mfma_f32_16x16x32_f16(k0, qfB[0], b, 0, 0, 0);
                    b = __builtin_amdgcn_mfma_f32_16x16x32_f16(k1, qfB[1], b, 0, 0, 0);
                    sB[f] = b;
                }
            }

            half8 pA0, pA1, pB0, pB1;
            if (actA) softmax_half(sA, t == boundA, j0, qrowA, col, quad, mA, lA, oA, pbuf, pA0, pA1);
            if (actB) softmax_half(sB, t == boundB, j0, qrowB, col, quad, mB, lB, oB, pbuf, pB0, pB1);

            // O^T += V^T * P^T : V fragments SHARED between both halves
            #pragma unroll
            for (int mc = 0; mc < 4; ++mc) {
                const _Float16* vr = Vs + (mc * 16 + col) * PADK + quad * 8;
                const half8 v0 = *(const half8*)(vr);
                const half8 v1 = *(const half8*)(vr + 32);
                if (actA) {
                    oA[mc] = __builtin_amdgcn_mfma_f32_16x16x32_f16(v0, pA0, oA[mc], 0, 0, 0);
                    oA[mc] = __builtin_amdgcn_mfma_f32_16x16x32_f16(v1, pA1, oA[mc], 0, 0, 0);
                }
                if (actB) {
                    oB[mc] = __builtin_amdgcn_mfma_f32_16x16x32_f16(v0, pB0, oB[mc], 0, 0, 0);
                    oB[mc] = __builtin_amdgcn_mfma_f32_16x16x32_f16(v1, pB1, oB[mc], 0, 0, 0);
                }
            }
        }
    }

    // epilogue: divide by l, store fp32. Out [B,H,L,D]
    {
        const float inv = 1.f / lA;
        float* op = Og + ((size_t)bh * NL + qrowA) * ND;
        #pragma unroll
        for (int mc = 0; mc < 4; ++mc) {
            float4 o;
            o.x = oA[mc][0] * inv; o.y = oA[mc][1] * inv;
            o.z = oA[mc][2] * inv; o.w = oA[mc][3] * inv;
            *(float4*)(op + mc * 16 + quad * 4) = o;
        }
    }
    {
        const float inv = 1.f / lB;
        float* op = Og + ((size_t)bh * NL + qrowB) * ND;
        #pragma unroll
        for (int mc = 0; mc < 4; ++mc) {
            float4 o;
            o.x = oB[mc][0] * inv; o.y = oB[mc][1] * inv;
            o.z = oB[mc][2] * inv; o.w = oB[mc][3] * inv;
            *(float4*)(op + mc * 16 + quad * 4) = o;
        }
    }
}

// ===================== fallback (round-2 kernel, passed) =====================
__global__ __launch_bounds__(256)
void lsattn_fb(const float* __restrict__ Qg,
               const float* __restrict__ Kg,
               const float* __restrict__ Vg,
               float* __restrict__ Og) {
    __shared__ alignas(16) unsigned short Kh[64 * PADK];
    __shared__ alignas(16) unsigned short Kl[64 * PADK];
    __shared__ alignas(16) unsigned short Vh[64 * PADK];

    const int qt   = 31 - (int)blockIdx.x;
    const int bh   = blockIdx.y;
    const int tid  = threadIdx.x;
    const int lane = tid & 63;
    const int w    = tid >> 6;
    const int col  = lane & 15;
    const int quad = lane >> 4;
    const int qrow = qt * 64 + w * 16 + col;

    short8 qhi[2], qlo[2];
    {
        const float* qp = Qg + ((bh >> 4) * NL + qrow) * (NH * ND) + (bh & 15) * ND + quad * 8;
        #pragma unroll
        for (int c = 0; c < 2; ++c) {
            float qv[8];
            *(float4*)(qv + 0) = *(const float4*)(qp + c * 32);
            *(float4*)(qv + 4) = *(const float4*)(qp + c * 32 + 4);
            #pragma unroll
            for (int j = 0; j < 8; ++j) {
                unsigned short h = f2bf(qv[j]);
                qhi[c][j] = (short)h;
                qlo[c][j] = (short)f2bf(qv[j] - bf2f(h));
            }
        }
    }
    floatx4 ofrag[4];
    #pragma unroll
    for (int i = 0; i < 4; ++i) ofrag[i] = floatx4{0.f, 0.f, 0.f, 0.f};
    float m_run = -1e30f, l_run = 0.f;
    const int skey  = tid >> 2;
    const int sdb   = (tid & 3) * 16;
    const int gbase = (bh >> 4) * NL * NH * ND + (bh & 15) * ND;

    for (int t = 0; t <= qt; ++t) {
        const int j0 = t * 64;
        __syncthreads();
        {
            const int gro = gbase + (j0 + skey) * (NH * ND) + sdb;
            float kv[16], vv[16];
            #pragma unroll
            for (int i = 0; i < 16; i += 4) {
                *(float4*)(kv + i) = *(const float4*)(Kg + gro + i);
                *(float4*)(vv + i) = *(const float4*)(Vg + gro + i);
            }
            short8 h0, h1, l0, l1;
            #pragma unroll
            for (int j = 0; j < 8; ++j) {
                unsigned short h = f2bf(kv[j]);
                h0[j] = (short)h; l0[j] = (short)f2bf(kv[j] - bf2f(h));
                unsigned short g = f2bf(kv[8 + j]);
                h1[j] = (short)g; l1[j] = (short)f2bf(kv[8 + j] - bf2f(g));
            }
            *(short8*)(Kh + skey * PADK + sdb)     = h0;
            *(short8*)(Kh + skey * PADK + sdb + 8) = h1;
            *(short8*)(Kl + skey * PADK + sdb)     = l0;
            *(short8*)(Kl + skey * PADK + sdb + 8) = l1;
            #pragma unroll
            for (int i = 0; i < 16; ++i) Vh[(sdb + i) * PADK + skey] = f2bf(vv[i]);
        }
        __syncthreads();

        floatx4 stf[4];
        #pragma unroll
        for (int f = 0; f < 4; ++f) {
            floatx4 acc = floatx4{0.f, 0.f, 0.f, 0.f};
            #pragma unroll
            for (int c = 0; c < 2; ++c) {
                short8 kh = *(const short8*)(Kh + (f * 16 + col) * PADK + c * 32 + quad * 8);
                short8 kl = *(const short8*)(Kl + (f * 16 + col) * PADK + c * 32 + quad * 8);
                acc = __builtin_amdgcn_mfma_f32_16x16x32_bf16(kh, qhi[c], acc, 0, 0, 0);
                acc = __builtin_amdgcn_mfma_f32_16x16x32_bf16(kl, qhi[c], acc, 0, 0, 0);
                acc = __builtin_amdgcn_mfma_f32_16x16x32_bf16(kh, qlo[c], acc, 0, 0, 0);
            }
            stf[f] = acc;
        }
        if (t == qt) {
            #pragma unroll
            for (int f = 0; f < 4; ++f)
                #pragma unroll
                for (int r = 0; r < 4; ++r) {
                    const int key = j0 + f * 16 + quad * 4 + r;
                    if (key > qrow) stf[f][r] = -1e30f;
                }
        }
        float mt = -1e30f;
        #pragma unroll
        for (int f = 0; f < 4; ++f)
            #pragma unroll
            for (int r = 0; r < 4; ++r) mt = fmaxf(mt, stf[f][r]);
        mt = fmaxf(mt, __shfl_xor(mt, 16));
        mt = fmaxf(mt, __shfl_xor(mt, 32));
        const float m_new = fmaxf(m_run, mt);
        const float alpha = __expf(m_run - m_new);
        float ls = 0.f;
        #pragma unroll
        for (int f = 0; f < 4; ++f)
            #pragma unroll
            for (int r = 0; r < 4; ++r) {
                const float p = __expf(stf[f][r] - m_new);
                stf[f][r] = p; ls += p;
            }
        ls += __shfl_xor(ls, 16);
        ls += __shfl_xor(ls, 32);
        l_run = l_run * alpha + ls;
        m_run = m_new;
        #pragma unroll
        for (int mc = 0; mc < 4; ++mc) ofrag[mc] *= alpha;

        short8 pfrag[2];
        #pragma unroll
        for (int kc = 0; kc < 2; ++kc) {
            #pragma unroll
            for (int jj = 0; jj < 8; ++jj) {
                const int r  = jj & 3;
                const int sq = (quad & 1) * 2 + (jj >> 2);
                const int sl = col + (sq << 4);
                const float va = __shfl(stf[kc * 2 + 0][r], sl);
                const float vb = __shfl(stf[kc * 2 + 1][r], sl);
                pfrag[kc][jj] = (short)f2bf((quad & 2) ? vb : va);
            }
        }
        #pragma unroll
        for (int mc = 0; mc < 4; ++mc) {
            #pragma unroll
            for (int kc = 0; kc < 2; ++kc) {
                short8 vf = *(const short8*)(Vh + (mc * 16 + col) * PADK + kc * 32 + quad * 8);
                ofrag[mc] = __builtin_amdgcn_mfma_f32_16x16x32_bf16(vf, pfrag[kc], ofrag[mc], 0, 0, 0);
            }
        }
    }
    const float inv = 1.f / l_run;
    float* op = Og + ((size_t)bh * NL + qrow) * ND;
    #pragma unroll
    for (int mc = 0; mc < 4; ++mc) {
        float4 o;
        o.x = ofrag[mc][0] * inv; o.y = ofrag[mc][1] * inv;
        o.z = ofrag[mc][2] * inv; o.w = ofrag[mc][3] * inv;
        *(float4*)(op + mc * 16 + quad * 4) = o;
    }
}

extern "C" void kernel_launch(void* const* d_in, const int* in_sizes, int n_in,
                              void* d_out, int out_size, void* d_ws, size_t ws_size,
                              hipStream_t stream) {
    const float* Q = (const float*)d_in[0];
    const float* K = (const float*)d_in[1];
    const float* V = (const float*)d_in[2];
    float* O = (float*)d_out;

    const size_t elems = (size_t)NB * NL * NH * ND;          // 8,388,608
    if (ws_size >= 2 * elems * sizeof(_Float16)) {           // 32 MiB needed
        _Float16* Kf = (_Float16*)d_ws;
        _Float16* Vt = Kf + elems;
        conv_kv<<<dim3(32, 64), dim3(256), 0, stream>>>(K, V, Kf, Vt);
        lsattn_main<<<dim3(512), dim3(512), 0, stream>>>(Q, Kf, Vt, O);
    } else {
        lsattn_fb<<<dim3(32, 64), dim3(256), 0, stream>>>(Q, K, V, O);
    }
}

// Round 2
// 187.588 us; speedup vs baseline: 1.1158x; 1.1158x over previous
//
#include <hip/hip_runtime.h>

// logsparseAttention == plain CAUSAL attention (no scale) at L=2048, SUB_LEN=5.
// Q,K,V [B,L,H,D] fp32; Out [B,H,L,D] fp32.  B=4, L=2048, H=16, D=64.
// R7: 32x32x16 MFMA path (halves K/V LDS fragment reads AND MFMA instr count
//     per query) on R5's proven occupancy structure:
//  - 256-thread blocks (4 waves x 32q), waves 0-1 -> supertile pr,
//    waves 2-3 -> 31-pr; grid 1024 => 4 blocks/CU, 4 independent barrier
//    domains/CU (R6's 2-domain regression reverted), identical compute per
//    block (66 wave-tiles).
//  - Ks/Vs unpadded [64][64] fp16 with XOR swizzle (elem ^= (row&7)<<3):
//    32-row b128 frag reads conflict-free; staging writes stay linear-in-row.
//  - P via wave-private blocked buffer [key>>3][q][key&7]: conflict-free
//    b64 writes / b128 reads by construction.
//  - diagonal tiles: wq==0 waves skip the fully-masked upper 32 keys
//    (half the S/PV MFMAs on the diagonal).
//  - exp2-domain softmax (K pre-scaled by log2e) + defer-max THR=8 kept.

typedef __attribute__((ext_vector_type(8))) short short8;
typedef __attribute__((ext_vector_type(4))) float floatx4;
typedef __attribute__((ext_vector_type(16))) float floatx16;
typedef _Float16 half8 __attribute__((ext_vector_type(8)));
typedef _Float16 half4 __attribute__((ext_vector_type(4)));

#define NB 4
#define NL 2048
#define NH 16
#define ND 64
#define PADK 72   // fallback kernel only
#define LOG2E 1.44269504088896340736f

// swizzled elem index into a [64][64] fp16 tile; col8 must be 8-elem aligned
#define KSW(row, col8) (((row) << 6) + ((col8) ^ (((row) & 7) << 3)))

static __device__ __forceinline__ unsigned short f2bf(float f) {
    unsigned int u = __float_as_uint(f);
    u += 0x7fff + ((u >> 16) & 1);
    return (unsigned short)(u >> 16);
}
static __device__ __forceinline__ float bf2f(unsigned short h) {
    return __uint_as_float(((unsigned int)h) << 16);
}
static __device__ __forceinline__ floatx16 fzero16() {
    floatx16 z;
    #pragma unroll
    for (int i = 0; i < 16; ++i) z[i] = 0.f;
    return z;
}

// ---- fused prepass: K -> Kf [bh][key][d] fp16 * log2(e); V -> Vt [bh][d][key] fp16
__global__ __launch_bounds__(256)
void conv_kv(const float* __restrict__ Kg, const float* __restrict__ Vg,
             _Float16* __restrict__ Kf, _Float16* __restrict__ Vt) {
    __shared__ float tile[64][65];
    const int kt = blockIdx.x;       // key tile 0..31
    const int bh = blockIdx.y;       // 0..63
    const int b  = bh >> 4, h = bh & 15;
    const int t  = threadIdx.x;
    const int row = t >> 2;          // 0..63
    const int seg = (t & 3) * 16;    // 0..48
    const size_t gsrc = (((size_t)(b * NL + kt * 64 + row) * NH + h) << 6) + seg;
    {   // K: vectorized convert, folded log2(e) scale (exp2-domain softmax)
        float kv[16];
        #pragma unroll
        for (int i = 0; i < 16; i += 4) *(float4*)(kv + i) = *(const float4*)(Kg + gsrc + i);
        half8 o0, o1;
        #pragma unroll
        for (int j2 = 0; j2 < 8; ++j2) {
            o0[j2] = (_Float16)(kv[j2] * LOG2E);
            o1[j2] = (_Float16)(kv[8 + j2] * LOG2E);
        }
        _Float16* kd = Kf + (((size_t)(bh * NL + kt * 64 + row)) << 6) + seg;
        *(half8*)kd = o0;
        *(half8*)(kd + 8) = o1;
    }
    {   // V phase 1: fp32 tile into LDS
        #pragma unroll
        for (int i = 0; i < 16; i += 4) {
            float4 v = *(const float4*)(Vg + gsrc + i);
            tile[row][seg + i + 0] = v.x;
            tile[row][seg + i + 1] = v.y;
            tile[row][seg + i + 2] = v.z;
            tile[row][seg + i + 3] = v.w;
        }
    }
    __syncthreads();
    #pragma unroll
    for (int pass = 0; pass < 2; ++pass) {   // V phase 2: transpose out as fp16
        const int d  = pass * 32 + (t >> 3);
        const int kk = (t & 7) * 8;
        half8 o;
        #pragma unroll
        for (int j2 = 0; j2 < 8; ++j2) o[j2] = (_Float16)tile[kk + j2][d];
        *(half8*)(Vt + (((size_t)(bh * 64 + d)) << 11) + kt * 64 + kk) = o;
    }
}

// ------------------------------- main kernel --------------------------------
__global__ __launch_bounds__(256, 4)
void lsattn_main(const float* __restrict__ Qg,
                 const _Float16* __restrict__ Kf,
                 const _Float16* __restrict__ Vt,
                 float* __restrict__ Og) {
    __shared__ alignas(16) _Float16 Ks[64 * 64];           // [key][d], swizzled
    __shared__ alignas(16) _Float16 Vs[64 * 64];           // [d][key], swizzled
    __shared__ alignas(16) _Float16 Ps[4 * 8 * 32 * 8];    // per-wave [slice][q][8]

    const int id   = (int)blockIdx.x;        // 0..1023
    const int bh   = id & 63;                // XCD = id%8 -> 8 heads/XCD ~ L2
    const int pr   = id >> 6;                // 0..15
    const int tid  = threadIdx.x;
    const int lane = tid & 63;
    const int w    = tid >> 6;               // wave 0..3
    const int wq   = w & 1;                  // 32-q slice within supertile
    const int lq   = lane & 31;              // query col (C/D: col = lane&31)
    const int hi   = lane >> 5;

    const int sa   = (w < 2) ? pr : 31 - pr; // this wave's 64-q supertile
    const int qrow = sa * 64 + wq * 32 + lq;
    const int TB   = 31 - pr;                // block stages tiles 0..TB (union)

    // Q fragments fp32->fp16, B-operand layout: lane holds Q[qrow][c*16+hi*8+j]
    half8 qf[4];
    {
        const float* qp = Qg + (((size_t)((bh >> 4) * NL + qrow) * NH + (bh & 15)) << 6) + hi * 8;
        #pragma unroll
        for (int c = 0; c < 4; ++c) {
            float4 a = *(const float4*)(qp + c * 16);
            float4 b = *(const float4*)(qp + c * 16 + 4);
            qf[c][0] = (_Float16)a.x; qf[c][1] = (_Float16)a.y;
            qf[c][2] = (_Float16)a.z; qf[c][3] = (_Float16)a.w;
            qf[c][4] = (_Float16)b.x; qf[c][5] = (_Float16)b.y;
            qf[c][6] = (_Float16)b.z; qf[c][7] = (_Float16)b.w;
        }
    }

    floatx16 o0 = fzero16(), o1 = fzero16();   // O^T[d 0..31][q], O^T[d 32..63][q]
    float m_run = -1e30f, l_run = 0.f;

    // staging: thread covers 16B of rows srow and srow+32; 256 thr x 4 x 16B = 16KB
    const int srow = tid >> 3;          // 0..31
    const int sseg = (tid & 7) * 8;     // 0..56
    const _Float16* kgb = Kf + ((size_t)bh * NL + srow) * 64 + sseg;               // + t*4096
    const _Float16* vgb = Vt + ((size_t)bh << 17) + (size_t)srow * NL + sseg;      // + t*64
    _Float16* pbuf = Ps + w * 2048;

    // prefetch tile 0 into registers
    half8 k0 = *(const half8*)(kgb);
    half8 k1 = *(const half8*)(kgb + 2048);
    half8 v0 = *(const half8*)(vgb);
    half8 v1 = *(const half8*)(vgb + 32 * NL);

    for (int t = 0; t <= TB; ++t) {
        __syncthreads();                 // tile t-1 consumers done
        *(half8*)(Ks + KSW(srow,      sseg)) = k0;
        *(half8*)(Ks + KSW(srow + 32, sseg)) = k1;
        *(half8*)(Vs + KSW(srow,      sseg)) = v0;
        *(half8*)(Vs + KSW(srow + 32, sseg)) = v1;
        if (t < TB) {                    // issue next tile's loads BEFORE barrier
            k0 = *(const half8*)(kgb + (size_t)(t + 1) * 4096);
            k1 = *(const half8*)(kgb + (size_t)(t + 1) * 4096 + 2048);
            v0 = *(const half8*)(vgb + (t + 1) * 64);
            v1 = *(const half8*)(vgb + (t + 1) * 64 + 32 * NL);
        }
        __syncthreads();                 // tile t visible

        if (t > sa) continue;            // inactive wave still stages above

        const bool diag  = (t == sa);
        const bool skip1 = diag && (wq == 0);   // upper 32 keys fully masked

        // S^T = K * Q^T : two 32(key) x 32(q) C-tiles, K-dim = D = 64
        floatx16 s0 = fzero16(), s1;
        #pragma unroll
        for (int c = 0; c < 4; ++c) {
            half8 kf = *(const half8*)(Ks + KSW(lq, c * 16 + hi * 8));
            s0 = __builtin_amdgcn_mfma_f32_32x32x16_f16(kf, qf[c], s0, 0, 0, 0);
        }
        if (!skip1) {
            s1 = fzero16();
            #pragma unroll
            for (int c = 0; c < 4; ++c) {
                half8 kf = *(const half8*)(Ks + KSW(32 + lq, c * 16 + hi * 8));
                s1 = __builtin_amdgcn_mfma_f32_32x32x16_f16(kf, qf[c], s1, 0, 0, 0);
            }
        }

        // causal mask on diagonal tile; lane's reg -> key = (r&3)+8*(r>>2)+4*hi
        if (diag) {
            if (wq == 0) {
                #pragma unroll
                for (int reg = 0; reg < 16; ++reg) {
                    const int key = (reg & 3) + ((reg >> 2) << 3) + (hi << 2);
                    if (key > lq) s0[reg] = -1e30f;
                }
            } else {
                #pragma unroll
                for (int reg = 0; reg < 16; ++reg) {
                    const int key = (reg & 3) + ((reg >> 2) << 3) + (hi << 2);
                    if (key > lq) s1[reg] = -1e30f;   // key 32+.. vs qrow 32+lq
                }
            }
        }

        // online softmax per query column (lane pair {lq, lq+32})
        float mt = s0[0];
        #pragma unroll
        for (int reg = 1; reg < 16; ++reg) mt = fmaxf(mt, s0[reg]);
        if (!skip1) {
            #pragma unroll
            for (int reg = 0; reg < 16; ++reg) mt = fmaxf(mt, s1[reg]);
        }
        mt = fmaxf(mt, __shfl_xor(mt, 32));
        if (__any(mt > m_run + 8.f)) {    // defer-max: P bounded by 2^8
            const float mn = fmaxf(m_run, mt);
            const float al = __builtin_amdgcn_exp2f(m_run - mn);
            #pragma unroll
            for (int i = 0; i < 16; ++i) { o0[i] *= al; o1[i] *= al; }
            l_run *= al;
            m_run = mn;
        }
        float ls = 0.f;
        #pragma unroll
        for (int s = 0; s < 4; ++s) {     // slice s covers keys 8s+4hi+(0..3)
            half4 hp;
            #pragma unroll
            for (int r = 0; r < 4; ++r) {
                const float p = __builtin_amdgcn_exp2f(s0[s * 4 + r] - m_run);
                ls += p; hp[r] = (_Float16)p;
            }
            *(half4*)(pbuf + (s * 32 + lq) * 8 + hi * 4) = hp;
        }
        if (!skip1) {
            #pragma unroll
            for (int s = 0; s < 4; ++s) {
                half4 hp;
                #pragma unroll
                for (int r = 0; r < 4; ++r) {
                    const float p = __builtin_amdgcn_exp2f(s1[s * 4 + r] - m_run);
                    ls += p; hp[r] = (_Float16)p;
                }
                *(half4*)(pbuf + ((4 + s) * 32 + lq) * 8 + hi * 4) = hp;
            }
        }
        ls += __shfl_xor(ls, 32);
        l_run += ls;

        // O^T += V^T * P^T   (pbuf wave-private: no barrier needed)
        const int cmax = skip1 ? 2 : 4;
        for (int c = 0; c < cmax; ++c) {
            half8 pf  = *(const half8*)(pbuf + ((c * 2 + hi) * 32 + lq) * 8);
            half8 vf0 = *(const half8*)(Vs + KSW(lq,      c * 16 + hi * 8));
            half8 vf1 = *(const half8*)(Vs + KSW(32 + lq, c * 16 + hi * 8));
            o0 = __builtin_amdgcn_mfma_f32_32x32x16_f16(vf0, pf, o0, 0, 0, 0);
            o1 = __builtin_amdgcn_mfma_f32_32x32x16_f16(vf1, pf, o1, 0, 0, 0);
        }
    }

    // epilogue: lane holds O[d = dt*32 + 4hi + r + 8s][q = lq]; divide by l, store
    const float inv = 1.f / l_run;
    float* op = Og + ((size_t)bh * NL + qrow) * ND;
    #pragma unroll
    for (int s = 0; s < 4; ++s) {
        float4 x, y;
        x.x = o0[s * 4 + 0] * inv; x.y = o0[s * 4 + 1] * inv;
        x.z = o0[s * 4 + 2] * inv; x.w = o0[s * 4 + 3] * inv;
        *(float4*)(op + s * 8 + hi * 4) = x;
        y.x = o1[s * 4 + 0] * inv; y.y = o1[s * 4 + 1] * inv;
        y.z = o1[s * 4 + 2] * inv; y.w = o1[s * 4 + 3] * inv;
        *(float4*)(op + 32 + s * 8 + hi * 4) = y;
    }
}

// ===================== fallback (round-2 kernel, passed) =====================
__global__ __launch_bounds__(256)
void lsattn_fb(const float* __restrict__ Qg,
               const float* __restrict__ Kg,
               const float* __restrict__ Vg,
               float* __restrict__ Og) {
    __shared__ alignas(16) unsigned short Kh[64 * PADK];
    __shared__ alignas(16) unsigned short Kl[64 * PADK];
    __shared__ alignas(16) unsigned short Vh[64 * PADK];

    const int qt   = 31 - (int)blockIdx.x;
    const int bh   = blockIdx.y;
    const int tid  = threadIdx.x;
    const int lane = tid & 63;
    const int w    = tid >> 6;
    const int col  = lane & 15;
    const int quad = lane >> 4;
    const int qrow = qt * 64 + w * 16 + col;

    short8 qhi[2], qlo[2];
    {
        const float* qp = Qg + ((bh >> 4) * NL + qrow) * (NH * ND) + (bh & 15) * ND + quad * 8;
        #pragma unroll
        for (int c = 0; c < 2; ++c) {
            float qv[8];
            *(float4*)(qv + 0) = *(const float4*)(qp + c * 32);
            *(float4*)(qv + 4) = *(const float4*)(qp + c * 32 + 4);
            #pragma unroll
            for (int j = 0; j < 8; ++j) {
                unsigned short h = f2bf(qv[j]);
                qhi[c][j] = (short)h;
                qlo[c][j] = (short)f2bf(qv[j] - bf2f(h));
            }
        }
    }
    floatx4 ofrag[4];
    #pragma unroll
    for (int i = 0; i < 4; ++i) ofrag[i] = floatx4{0.f, 0.f, 0.f, 0.f};
    float m_run = -1e30f, l_run = 0.f;
    const int skey  = tid >> 2;
    const int sdb   = (tid & 3) * 16;
    const int gbase = (bh >> 4) * NL * NH * ND + (bh & 15) * ND;

    for (int t = 0; t <= qt; ++t) {
        const int j0 = t * 64;
        __syncthreads();
        {
            const int gro = gbase + (j0 + skey) * (NH * ND) + sdb;
            float kv[16], vv[16];
            #pragma unroll
            for (int i = 0; i < 16; i += 4) {
                *(float4*)(kv + i) = *(const float4*)(Kg + gro + i);
                *(float4*)(vv + i) = *(const float4*)(Vg + gro + i);
            }
            short8 h0, h1, l0, l1;
            #pragma unroll
            for (int j = 0; j < 8; ++j) {
                unsigned short h = f2bf(kv[j]);
                h0[j] = (short)h; l0[j] = (short)f2bf(kv[j] - bf2f(h));
                unsigned short g = f2bf(kv[8 + j]);
                h1[j] = (short)g; l1[j] = (short)f2bf(kv[8 + j] - bf2f(g));
            }
            *(short8*)(Kh + skey * PADK + sdb)     = h0;
            *(short8*)(Kh + skey * PADK + sdb + 8) = h1;
            *(short8*)(Kl + skey * PADK + sdb)     = l0;
            *(short8*)(Kl + skey * PADK + sdb + 8) = l1;
            #pragma unroll
            for (int i = 0; i < 16; ++i) Vh[(sdb + i) * PADK + skey] = f2bf(vv[i]);
        }
        __syncthreads();

        floatx4 stf[4];
        #pragma unroll
        for (int f = 0; f < 4; ++f) {
            floatx4 acc = floatx4{0.f, 0.f, 0.f, 0.f};
            #pragma unroll
            for (int c = 0; c < 2; ++c) {
                short8 kh = *(const short8*)(Kh + (f * 16 + col) * PADK + c * 32 + quad * 8);
                short8 kl = *(const short8*)(Kl + (f * 16 + col) * PADK + c * 32 + quad * 8);
                acc = __builtin_amdgcn_mfma_f32_16x16x32_bf16(kh, qhi[c], acc, 0, 0, 0);
                acc = __builtin_amdgcn_mfma_f32_16x16x32_bf16(kl, qhi[c], acc, 0, 0, 0);
                acc = __builtin_amdgcn_mfma_f32_16x16x32_bf16(kh, qlo[c], acc, 0, 0, 0);
            }
            stf[f] = acc;
        }
        if (t == qt) {
            #pragma unroll
            for (int f = 0; f < 4; ++f)
                #pragma unroll
                for (int r = 0; r < 4; ++r) {
                    const int key = j0 + f * 16 + quad * 4 + r;
                    if (key > qrow) stf[f][r] = -1e30f;
                }
        }
        float mt = -1e30f;
        #pragma unroll
        for (int f = 0; f < 4; ++f)
            #pragma unroll
            for (int r = 0; r < 4; ++r) mt = fmaxf(mt, stf[f][r]);
        mt = fmaxf(mt, __shfl_xor(mt, 16));
        mt = fmaxf(mt, __shfl_xor(mt, 32));
        const float m_new = fmaxf(m_run, mt);
        const float alpha = __expf(m_run - m_new);
        float ls = 0.f;
        #pragma unroll
        for (int f = 0; f < 4; ++f)
            #pragma unroll
            for (int r = 0; r < 4; ++r) {
                const float p = __expf(stf[f][r] - m_new);
                stf[f][r] = p; ls += p;
            }
        ls += __shfl_xor(ls, 16);
        ls += __shfl_xor(ls, 32);
        l_run = l_run * alpha + ls;
        m_run = m_new;
        #pragma unroll
        for (int mc = 0; mc < 4; ++mc) ofrag[mc] *= alpha;

        short8 pfrag[2];
        #pragma unroll
        for (int kc = 0; kc < 2; ++kc) {
            #pragma unroll
            for (int jj = 0; jj < 8; ++jj) {
                const int r  = jj & 3;
                const int sq = (quad & 1) * 2 + (jj >> 2);
                const int sl = col + (sq << 4);
                const float va = __shfl(stf[kc * 2 + 0][r], sl);
                const float vb = __shfl(stf[kc * 2 + 1][r], sl);
                pfrag[kc][jj] = (short)f2bf((quad & 2) ? vb : va);
            }
        }
        #pragma unroll
        for (int mc = 0; mc < 4; ++mc) {
            #pragma unroll
            for (int kc = 0; kc < 2; ++kc) {
                short8 vf = *(const short8*)(Vh + (mc * 16 + col) * PADK + kc * 32 + quad * 8);
                ofrag[mc] = __builtin_amdgcn_mfma_f32_16x16x32_bf16(vf, pfrag[kc], ofrag[mc], 0, 0, 0);
            }
        }
    }
    const float inv = 1.f / l_run;
    float* op = Og + ((size_t)bh * NL + qrow) * ND;
    #pragma unroll
    for (int mc = 0; mc < 4; ++mc) {
        float4 o;
        o.x = ofrag[mc][0] * inv; o.y = ofrag[mc][1] * inv;
        o.z = ofrag[mc][2] * inv; o.w = ofrag[mc][3] * inv;
        *(float4*)(op + mc * 16 + quad * 4) = o;
    }
}

extern "C" void kernel_launch(void* const* d_in, const int* in_sizes, int n_in,
                              void* d_out, int out_size, void* d_ws, size_t ws_size,
                              hipStream_t stream) {
    const float* Q = (const float*)d_in[0];
    const float* K = (const float*)d_in[1];
    const float* V = (const float*)d_in[2];
    float* O = (float*)d_out;

    const size_t elems = (size_t)NB * NL * NH * ND;          // 8,388,608
    if (ws_size >= 2 * elems * sizeof(_Float16)) {           // 32 MiB needed
        _Float16* Kf = (_Float16*)d_ws;
        _Float16* Vt = Kf + elems;
        conv_kv<<<dim3(32, 64), dim3(256), 0, stream>>>(K, V, Kf, Vt);
        lsattn_main<<<dim3(1024), dim3(256), 0, stream>>>(Q, Kf, Vt, O);
    } else {
        lsattn_fb<<<dim3(32, 64), dim3(256), 0, stream>>>(Q, K, V, O);
    }
}